// Round 4
// baseline (287.440 us; speedup 1.0000x reference)
//
#include <hip/hip_runtime.h>

// Problem constants: B=4, SEQ=4096, D=64, BS=32, V=512, R=128, P=33024
#define Bn   4
#define SEQn 4096
#define Dn   64
#define BSn  32
#define Vn   512
#define Rn   128
#define PPB  8256   // p's per batch = R*(R+1)/2

// ---------------- Phase 1: scores[b][m][v] = sum_d q[b][m][d] * emb[b][v][d]
#define TM   64
#define TVb  128
#define QP   68
#define EP   132

__global__ __launch_bounds__(256) void scores_kernel(
    const float* __restrict__ q, const float* __restrict__ emb,
    float* __restrict__ scores)
{
  __shared__ float sq[Dn * QP];   // [d][m]
  __shared__ float se[Dn * EP];   // [d][v]

  int bx   = blockIdx.x;
  int vblk = bx & 3;
  int bblk = (bx >> 2) & 3;
  int mblk = bx >> 4;
  int m0 = mblk * TM;
  int v0 = vblk * TVb;

  const float* qbase = q   + ((size_t)bblk * SEQn + m0) * Dn;
  const float* ebase = emb + ((size_t)bblk * Vn   + v0) * Dn;

  int t = threadIdx.x;
  for (int idx = t; idx < TM * Dn / 4; idx += 256) {
    int e = idx * 4;
    int m = e >> 6;
    int d = e & 63;
    float4 x = *(const float4*)(qbase + (size_t)m * Dn + d);
    sq[(d + 0) * QP + m] = x.x;
    sq[(d + 1) * QP + m] = x.y;
    sq[(d + 2) * QP + m] = x.z;
    sq[(d + 3) * QP + m] = x.w;
  }
  for (int idx = t; idx < TVb * Dn / 4; idx += 256) {
    int e = idx * 4;
    int v = e >> 6;
    int d = e & 63;
    float4 x = *(const float4*)(ebase + (size_t)v * Dn + d);
    se[(d + 0) * EP + v] = x.x;
    se[(d + 1) * EP + v] = x.y;
    se[(d + 2) * EP + v] = x.z;
    se[(d + 3) * EP + v] = x.w;
  }
  __syncthreads();

  int tx = t & 31;
  int ty = t >> 5;
  int ml = ty * 8;
  int vl = tx * 4;

  float acc[8][4];
#pragma unroll
  for (int r = 0; r < 8; ++r)
#pragma unroll
    for (int k = 0; k < 4; ++k) acc[r][k] = 0.0f;

#pragma unroll 4
  for (int d = 0; d < Dn; ++d) {
    float4 qa = *(const float4*)&sq[d * QP + ml];
    float4 qb = *(const float4*)&sq[d * QP + ml + 4];
    float4 ev = *(const float4*)&se[d * EP + vl];
    float qr[8] = {qa.x, qa.y, qa.z, qa.w, qb.x, qb.y, qb.z, qb.w};
    float ek[4] = {ev.x, ev.y, ev.z, ev.w};
#pragma unroll
    for (int r = 0; r < 8; ++r)
#pragma unroll
      for (int k = 0; k < 4; ++k) acc[r][k] += qr[r] * ek[k];
  }

  float* obase = scores + ((size_t)bblk * SEQn + m0) * Vn + v0;
#pragma unroll
  for (int r = 0; r < 8; ++r) {
    float4 st = {acc[r][0], acc[r][1], acc[r][2], acc[r][3]};
    *(float4*)(obase + (size_t)(ml + r) * Vn + vl) = st;
  }
}

// ---------------- Phase 2: gather, persistent paired-row blocks
// Block = (b, pair k): rows rA=127-k (big) and rB=k (small); (rA+1)+(rB+1)=129
// p's per block — exact balance. 256 blocks x 1024 threads.
// Each row's 64 KB score slab is processed as two 32 KB HALF-slabs
// (rows i in [16h,16h+16) serve output elements with int4-index 128h..128h+127
// of every p). Two 32 KB LDS buffers ping-pong: next half's global loads are
// issued into registers BEFORE the current gather phase, LDS-written after —
// staging latency hides behind ~17 gather iterations.
#define HS (16 * Vn)   // floats per half-slab = 8192 (32 KB)

__device__ __forceinline__ void gather_half(
    const float* __restrict__ buf, const int4* __restrict__ info4,
    float4* __restrict__ out4, int b, int r, int h, int tid)
{
  int np = r + 1;
  size_t p0 = (size_t)b * PPB + ((size_t)r * (r + 1)) / 2;
  int pq = tid >> 7;                 // 0..7: p-offset within a group of 8
  int l  = tid & 127;                // int4 index within the half
  int rowoff = (l >> 3) << 9;        // local row (l>>3) * 512
  int eo = 128 * h + l;              // int4 offset within p

  // software-pipelined info load (next iteration's load issues before stores)
  size_t pfirst = p0 + (pq < np ? pq : 0);
  int4 iv = info4[pfirst * 256 + eo];
  for (int pp = pq; pp < np; pp += 8) {
    int4 cur = iv;
    if (pp + 8 < np) iv = info4[(p0 + pp + 8) * 256 + eo];
    float4 o;
    o.x = buf[rowoff + cur.x];
    o.y = buf[rowoff + cur.y];
    o.z = buf[rowoff + cur.z];
    o.w = buf[rowoff + cur.w];
    out4[(p0 + pp) * 256 + eo] = o;
  }
}

__global__ __launch_bounds__(1024) void gather_kernel(
    const float* __restrict__ scores, const int* __restrict__ info,
    float* __restrict__ out)
{
  __shared__ float bufA[HS];
  __shared__ float bufB[HS];

  int blk = blockIdx.x;      // 0..255
  int b   = blk >> 6;
  int k   = blk & 63;
  int rA  = 127 - k;         // big row first
  int rB  = k;
  int tid = threadIdx.x;

  const int4* info4 = (const int4*)info;
  float4*     out4  = (float4*)out;

  // half hh: row = (hh<2?rA:rB), half h = hh&1; source is 2048 contiguous float4
  const float4* s0 = (const float4*)(scores + ((size_t)b * SEQn + (size_t)rA * BSn +  0) * Vn);
  const float4* s1 = (const float4*)(scores + ((size_t)b * SEQn + (size_t)rA * BSn + 16) * Vn);
  const float4* s2 = (const float4*)(scores + ((size_t)b * SEQn + (size_t)rB * BSn +  0) * Vn);
  const float4* s3 = (const float4*)(scores + ((size_t)b * SEQn + (size_t)rB * BSn + 16) * Vn);

  float4 r0, r1;

  // h0 -> A
  r0 = s0[tid]; r1 = s0[tid + 1024];
  ((float4*)bufA)[tid] = r0; ((float4*)bufA)[tid + 1024] = r1;
  // issue h1 loads (complete during gather h0)
  r0 = s1[tid]; r1 = s1[tid + 1024];
  __syncthreads();                       // A ready
  gather_half(bufA, info4, out4, b, rA, 0, tid);

  ((float4*)bufB)[tid] = r0; ((float4*)bufB)[tid + 1024] = r1;
  r0 = s2[tid]; r1 = s2[tid + 1024];     // issue h2
  __syncthreads();                       // B ready; all waves done reading A
  gather_half(bufB, info4, out4, b, rA, 1, tid);

  ((float4*)bufA)[tid] = r0; ((float4*)bufA)[tid + 1024] = r1;
  r0 = s3[tid]; r1 = s3[tid + 1024];     // issue h3
  __syncthreads();                       // A ready; all waves done reading B
  gather_half(bufA, info4, out4, b, rB, 0, tid);

  ((float4*)bufB)[tid] = r0; ((float4*)bufB)[tid + 1024] = r1;
  __syncthreads();                       // B ready; all waves done reading A
  gather_half(bufB, info4, out4, b, rB, 1, tid);
}

extern "C" void kernel_launch(void* const* d_in, const int* in_sizes, int n_in,
                              void* d_out, int out_size, void* d_ws, size_t ws_size,
                              hipStream_t stream) {
  const float* q    = (const float*)d_in[0];
  const float* emb  = (const float*)d_in[1];
  const int*   info = (const int*)d_in[2];
  // d_in[3]/d_in[4] (idxs_batch/idxs_row) derivable from tril structure.

  float* scores = (float*)d_ws;   // B*SEQ*V*4 = 32 MiB
  float* out    = (float*)d_out;

  int gemm_blocks = (SEQn / TM) * Bn * (Vn / TVb);   // 1024
  scores_kernel<<<gemm_blocks, 256, 0, stream>>>(q, emb, scores);

  gather_kernel<<<Bn * 64, 1024, 0, stream>>>(scores, info, out);
}